// Round 3
// baseline (783.314 us; speedup 1.0000x reference)
//
#include <hip/hip_runtime.h>
#include <float.h>
#include <math.h>

#define NROWS 65536
#define DIM 256
#define NCODES 2048
#define MARGIN 0.25f

typedef _Float16 f16x8 __attribute__((ext_vector_type(8)));
typedef _Float16 f16x4 __attribute__((ext_vector_type(4)));
typedef float    f32x4 __attribute__((ext_vector_type(4)));

// ws layout (bytes):
#define WS_WH     0         // 1 MB  codebook hi halves
#define WS_CBSQ   1048576   // 8 KB
#define WS_USAGE  1056768   // 8 KB
#define WS_ACCUM  1064960   // 4 B
#define WS_FCOUNT 1064964   // 4 B
#define WS_FLAGS  1064968   // 256 KB flagged row ids

__device__ __forceinline__ void ld16(const void* g, void* l) {
    __builtin_amdgcn_global_load_lds(
        (__attribute__((address_space(1))) void*)g,
        (__attribute__((address_space(3))) void*)l, 16, 0, 0);
}

// -------- split fp32 -> fp16 hi only, 8 elems/thread --------
__global__ void split_hi_kernel(const float* __restrict__ x, _Float16* __restrict__ hi) {
    int i = (blockIdx.x * 256 + threadIdx.x) * 8;
    float4 a = *(const float4*)(x + i);
    float4 b = *(const float4*)(x + i + 4);
    f16x8 h = { (_Float16)a.x, (_Float16)a.y, (_Float16)a.z, (_Float16)a.w,
                (_Float16)b.x, (_Float16)b.y, (_Float16)b.z, (_Float16)b.w };
    *(f16x8*)(hi + i) = h;
}

// -------- codebook prep: wh halves + exact fp32 sq-norms; one wave/code --------
__global__ void cbprep_kernel(const float* __restrict__ cb, _Float16* __restrict__ wh,
                              float* __restrict__ cbsq) {
    int wid  = (blockIdx.x * blockDim.x + threadIdx.x) >> 6;
    int lane = threadIdx.x & 63;
    const float4* c4 = (const float4*)cb;
    float4 v = c4[wid * 64 + lane];
    float s = v.x * v.x + v.y * v.y + v.z * v.z + v.w * v.w;
    #pragma unroll
    for (int m = 32; m >= 1; m >>= 1) s += __shfl_xor(s, m, 64);
    if (lane == 0) cbsq[wid] = s;
    f16x4 h = { (_Float16)v.x, (_Float16)v.y, (_Float16)v.z, (_Float16)v.w };
    ((f16x4*)wh)[wid * 64 + lane] = h;
}

// -------- phase 1: approx distances (hi*hi only), top-2 per row, flag close calls --------
// 512 blocks x 256 thr (4 waves, 2x2); wave tile 64 rows x 128 codes; 8 chunks of 256 codes.
__global__ __launch_bounds__(256, 2)
void argmin_kernel(const _Float16* __restrict__ zh, const _Float16* __restrict__ wh,
                   const float* __restrict__ cbsq, float* __restrict__ idx_out,
                   int* __restrict__ fcount, int* __restrict__ flags) {
    __shared__ _Float16 Ah[128 * 32];   // 8 KB
    __shared__ _Float16 Bh[256 * 32];   // 16 KB
    __shared__ float rD[2][128];
    __shared__ int   rI[2][128];
    __shared__ float r2[2][128];

    const int t    = threadIdx.x;
    const int wave = t >> 6;
    const int lane = t & 63;
    const int quad = lane >> 4;
    const int l15  = lane & 15;
    const int wr0  = (wave & 1) * 64;
    const int wc0  = (wave >> 1) * 128;
    const int row0 = blockIdx.x * 128;
    const int p8   = (quad ^ ((l15 >> 1) & 3)) * 8;

    float bd1[16], bd2[16];
    int   bi1[16];
    #pragma unroll
    for (int s = 0; s < 16; s++) { bd1[s] = FLT_MAX; bd2[s] = FLT_MAX; bi1[s] = 0; }

    for (int cc = 0; cc < 8; cc++) {
        f32x4 acc[4][8];
        #pragma unroll
        for (int i = 0; i < 4; i++)
            #pragma unroll
            for (int j = 0; j < 8; j++) acc[i][j] = (f32x4){0.f, 0.f, 0.f, 0.f};

        for (int kc = 0; kc < 8; kc++) {
            __syncthreads();
            #pragma unroll
            for (int it = 0; it < 2; it++) {
                int s = it * 256 + t;
                int r = s >> 2;
                int g = (s & 3) ^ ((r >> 1) & 3);
                ld16(zh + (size_t)(row0 + r) * 256 + kc * 32 + g * 8, &Ah[s * 8]);
            }
            #pragma unroll
            for (int it = 0; it < 4; it++) {
                int s = it * 256 + t;
                int n = s >> 2;
                int g = (s & 3) ^ ((n >> 1) & 3);
                ld16(wh + (size_t)(cc * 256 + n) * 256 + kc * 32 + g * 8, &Bh[s * 8]);
            }
            __syncthreads();

            f16x8 ah[4];
            #pragma unroll
            for (int i = 0; i < 4; i++)
                ah[i] = *(const f16x8*)&Ah[(wr0 + i * 16 + l15) * 32 + p8];
            #pragma unroll
            for (int j = 0; j < 8; j++) {
                f16x8 bh = *(const f16x8*)&Bh[(wc0 + j * 16 + l15) * 32 + p8];
                #pragma unroll
                for (int i = 0; i < 4; i++)
                    acc[i][j] = __builtin_amdgcn_mfma_f32_16x16x32_f16(ah[i], bh, acc[i][j], 0, 0, 0);
            }
        }

        // epilogue: approx d = cbsq - 2*dot ; track top-2 per lane-row
        #pragma unroll
        for (int j = 0; j < 8; j++) {
            int c = cc * 256 + wc0 + j * 16 + l15;
            float csq = cbsq[c];
            #pragma unroll
            for (int i = 0; i < 4; i++) {
                #pragma unroll
                for (int r = 0; r < 4; r++) {
                    float d = fmaf(-2.0f, acc[i][j][r], csq);
                    int s = i * 4 + r;
                    if (d < bd1[s]) { bd2[s] = bd1[s]; bd1[s] = d; bi1[s] = c; }
                    else            { bd2[s] = fminf(bd2[s], d); }
                }
            }
        }
    }

    // top-2 merge across the 16 lanes holding the same rows
    #pragma unroll
    for (int m = 1; m <= 8; m <<= 1) {
        #pragma unroll
        for (int s = 0; s < 16; s++) {
            float od1 = __shfl_xor(bd1[s], m, 64);
            int   oi1 = __shfl_xor(bi1[s], m, 64);
            float od2 = __shfl_xor(bd2[s], m, 64);
            if (od1 < bd1[s] || (od1 == bd1[s] && oi1 < bi1[s])) {
                bd2[s] = fminf(bd1[s], od2);
                bd1[s] = od1; bi1[s] = oi1;
            } else {
                bd2[s] = fminf(bd2[s], od1);
            }
        }
    }
    __syncthreads();
    if (l15 == 0) {
        #pragma unroll
        for (int i = 0; i < 4; i++)
            #pragma unroll
            for (int r = 0; r < 4; r++) {
                int row = wr0 + i * 16 + quad * 4 + r;
                rD[wave >> 1][row] = bd1[i * 4 + r];
                rI[wave >> 1][row] = bi1[i * 4 + r];
                r2[wave >> 1][row] = bd2[i * 4 + r];
            }
    }
    __syncthreads();
    if (t < 128) {
        float d1 = rD[0][t]; int i1 = rI[0][t]; float d2 = r2[0][t];
        float e1 = rD[1][t]; int j1 = rI[1][t]; float e2 = r2[1][t];
        if (e1 < d1 || (e1 == d1 && j1 < i1)) {
            d2 = fminf(d1, e2); d1 = e1; i1 = j1;
        } else {
            d2 = fminf(d2, e1);
        }
        int row = row0 + t;
        idx_out[row] = (float)i1;
        if (d2 - d1 < MARGIN) {
            int p = atomicAdd(fcount, 1);
            flags[p] = row;
        }
    }
}

// -------- phase 2: exact fp32 rescan of flagged rows (groups of 8 rows/block) --------
__global__ void refine_kernel(const float* __restrict__ z, const float* __restrict__ cb,
                              const float* __restrict__ cbsq, const int* __restrict__ fcount,
                              const int* __restrict__ flags, float* __restrict__ idx_f) {
    __shared__ float zrow[8 * 256];
    const int t = threadIdx.x;
    const int rr = t >> 5;      // row slot 0..7
    const int cs = t & 31;      // code lane 0..31
    const int count = *fcount;
    const int nb = (count + 7) >> 3;

    for (int g = blockIdx.x; g < nb; g += gridDim.x) {
        __syncthreads();
        int slot = (g << 3) + rr;
        int row = (slot < count) ? flags[slot] : -1;
        if (row >= 0) {
            const float4* z4 = (const float4*)z;
            float4 a = z4[(size_t)row * 64 + cs * 2];
            float4 b = z4[(size_t)row * 64 + cs * 2 + 1];
            *(float4*)&zrow[rr * 256 + cs * 8]     = a;
            *(float4*)&zrow[rr * 256 + cs * 8 + 4] = b;
        }
        __syncthreads();

        float d1 = FLT_MAX; int i1 = 0;
        if (row >= 0) {
            const float4* zl = (const float4*)&zrow[rr * 256];
            for (int k = 0; k < 64; k++) {
                int c = cs + (k << 5);                 // ascending per thread
                const float4* w4 = (const float4*)(cb + (size_t)c * 256);
                float ax = 0.f, ay = 0.f, az = 0.f, aw = 0.f;
                #pragma unroll 8
                for (int m = 0; m < 64; m++) {
                    float4 zv = zl[m];
                    float4 wv = w4[m];
                    ax = fmaf(zv.x, wv.x, ax);
                    ay = fmaf(zv.y, wv.y, ay);
                    az = fmaf(zv.z, wv.z, az);
                    aw = fmaf(zv.w, wv.w, aw);
                }
                float dot = (ax + ay) + (az + aw);
                float d = fmaf(-2.0f, dot, cbsq[c]);
                if (d < d1) { d1 = d; i1 = c; }
            }
        }
        // reduce across the 32 lanes of this row (xor <=16 stays in the half-wave)
        #pragma unroll
        for (int m = 1; m <= 16; m <<= 1) {
            float od = __shfl_xor(d1, m, 64);
            int   oi = __shfl_xor(i1, m, 64);
            if (od < d1 || (od == d1 && oi < i1)) { d1 = od; i1 = oi; }
        }
        if (cs == 0 && row >= 0) idx_f[row] = (float)i1;
    }
}

// -------- gather + STE + commitment partial + histogram: one wave per row --------
__global__ void gather_kernel(const float* __restrict__ z, const float* __restrict__ cb,
                              const float* __restrict__ idx_f, float* __restrict__ out,
                              int* __restrict__ usage, float* __restrict__ accum) {
    int lane = threadIdx.x & 63;
    int wid  = (blockIdx.x * blockDim.x + threadIdx.x) >> 6;
    const float4* z4  = (const float4*)z;
    const float4* cb4 = (const float4*)cb;
    float4* o4 = (float4*)out;

    float local = 0.0f;
    for (int r = wid; r < NROWS; r += 2048) {
        int idx = (int)idx_f[r];
        float4 w  = cb4[(size_t)idx * 64 + lane];
        float4 zv = z4[(size_t)r * 64 + lane];
        float4 d;
        d.x = w.x - zv.x; d.y = w.y - zv.y; d.z = w.z - zv.z; d.w = w.w - zv.w;
        float4 o;
        o.x = zv.x + d.x; o.y = zv.y + d.y; o.z = zv.z + d.z; o.w = zv.w + d.w;
        o4[(size_t)r * 64 + lane] = o;
        local = fmaf(d.x, d.x, local);
        local = fmaf(d.y, d.y, local);
        local = fmaf(d.z, d.z, local);
        local = fmaf(d.w, d.w, local);
        if (lane == 0) atomicAdd(&usage[idx], 1);
    }
    #pragma unroll
    for (int m = 32; m >= 1; m >>= 1) local += __shfl_xor(local, m, 64);
    if (lane == 0) atomicAdd(accum, local);
}

// -------- scalars: commitment mean + entropy loss --------
__global__ void finalize_kernel(const int* __restrict__ usage, const float* __restrict__ accum,
                                float* __restrict__ out2) {
    __shared__ float red[256];
    int t = threadIdx.x;
    float e = 0.0f;
    for (int b = t; b < NCODES; b += 256) {
        float p = (float)usage[b] * (1.0f / 65536.0f);
        e -= p * logf(p + 1e-10f);
    }
    red[t] = e;
    __syncthreads();
    if (t == 0) {
        float s = 0.0f;
        for (int k = 0; k < 256; k++) s += red[k];
        out2[0] = accum[0] / 16777216.0f;
        out2[1] = logf(2048.0f) - s;
    }
}

extern "C" void kernel_launch(void* const* d_in, const int* in_sizes, int n_in,
                              void* d_out, int out_size, void* d_ws, size_t ws_size,
                              hipStream_t stream) {
    const float* z  = (const float*)d_in[0];
    const float* cb = (const float*)d_in[1];

    float* out   = (float*)d_out;
    float* idx_f = out + (size_t)NROWS * DIM;
    float* out2  = idx_f + NROWS;

    // zh scratch in the zq output region (first 32 MB), overwritten by gather later
    _Float16* zh = (_Float16*)d_out;

    _Float16* wh    = (_Float16*)((char*)d_ws + WS_WH);
    float*    cbsq  = (float*)((char*)d_ws + WS_CBSQ);
    int*      usage = (int*)((char*)d_ws + WS_USAGE);
    float*    accum = (float*)((char*)d_ws + WS_ACCUM);
    int*      fcount= (int*)((char*)d_ws + WS_FCOUNT);
    int*      flags = (int*)((char*)d_ws + WS_FLAGS);

    hipMemsetAsync((char*)d_ws + WS_USAGE, 0, 8200, stream);   // usage + accum + fcount
    split_hi_kernel<<<8192, 256, 0, stream>>>(z, zh);
    cbprep_kernel<<<512, 256, 0, stream>>>(cb, wh, cbsq);
    argmin_kernel<<<512, 256, 0, stream>>>(zh, wh, cbsq, idx_f, fcount, flags);
    refine_kernel<<<256, 256, 0, stream>>>(z, cb, cbsq, fcount, flags, idx_f);
    gather_kernel<<<512, 256, 0, stream>>>(z, cb, idx_f, out, usage, accum);
    finalize_kernel<<<1, 256, 0, stream>>>(usage, accum, out2);
}

// Round 5
// 427.912 us; speedup vs baseline: 1.8306x; 1.8306x over previous
//
#include <hip/hip_runtime.h>
#include <float.h>
#include <math.h>

#define NROWS 65536
#define DIM 256
#define NCODES 2048
#define MARGIN 0.25f

typedef _Float16 f16x8 __attribute__((ext_vector_type(8)));
typedef _Float16 f16x4 __attribute__((ext_vector_type(4)));
typedef float    f32x4 __attribute__((ext_vector_type(4)));

// ws layout (bytes):
#define WS_WH     0          // 1 MB  codebook hi halves
#define WS_WL     1048576    // 1 MB  codebook lo halves
#define WS_CBSQ   2097152    // 8 KB
#define WS_USAGE  2105344    // 8 KB
#define WS_ACCUM  2113536    // 4 B
#define WS_FCOUNT 2113540    // 4 B
#define WS_FLAGS  2113544    // 256 KB flagged row ids

__device__ __forceinline__ void ld16(const void* g, void* l) {
    __builtin_amdgcn_global_load_lds(
        (__attribute__((address_space(1))) void*)g,
        (__attribute__((address_space(3))) void*)l, 16, 0, 0);
}

// -------- split fp32 -> fp16 hi only, 8 elems/thread --------
__global__ void split_hi_kernel(const float* __restrict__ x, _Float16* __restrict__ hi) {
    int i = (blockIdx.x * 256 + threadIdx.x) * 8;
    float4 a = *(const float4*)(x + i);
    float4 b = *(const float4*)(x + i + 4);
    f16x8 h = { (_Float16)a.x, (_Float16)a.y, (_Float16)a.z, (_Float16)a.w,
                (_Float16)b.x, (_Float16)b.y, (_Float16)b.z, (_Float16)b.w };
    *(f16x8*)(hi + i) = h;
}

// -------- codebook prep: wh+wl halves + exact fp32 sq-norms; one wave/code --------
__global__ void cbprep_kernel(const float* __restrict__ cb, _Float16* __restrict__ wh,
                              _Float16* __restrict__ wl, float* __restrict__ cbsq) {
    int wid  = (blockIdx.x * blockDim.x + threadIdx.x) >> 6;
    int lane = threadIdx.x & 63;
    const float4* c4 = (const float4*)cb;
    float4 v = c4[wid * 64 + lane];
    float s = v.x * v.x + v.y * v.y + v.z * v.z + v.w * v.w;
    #pragma unroll
    for (int m = 32; m >= 1; m >>= 1) s += __shfl_xor(s, m, 64);
    if (lane == 0) cbsq[wid] = s;
    f16x4 h = { (_Float16)v.x, (_Float16)v.y, (_Float16)v.z, (_Float16)v.w };
    f16x4 l = { (_Float16)(v.x - (float)h[0]), (_Float16)(v.y - (float)h[1]),
                (_Float16)(v.z - (float)h[2]), (_Float16)(v.w - (float)h[3]) };
    ((f16x4*)wh)[wid * 64 + lane] = h;
    ((f16x4*)wl)[wid * 64 + lane] = l;
}

// -------- phase 1: approx distances (hi*hi only), top-2 per row, flag close calls --------
__global__ __launch_bounds__(256, 2)
void argmin_kernel(const _Float16* __restrict__ zh, const _Float16* __restrict__ wh,
                   const float* __restrict__ cbsq, float* __restrict__ idx_out,
                   int* __restrict__ fcount, int* __restrict__ flags) {
    __shared__ _Float16 Ah[128 * 32];   // 8 KB
    __shared__ _Float16 Bh[256 * 32];   // 16 KB
    __shared__ float rD[2][128];
    __shared__ int   rI[2][128];
    __shared__ float r2[2][128];

    const int t    = threadIdx.x;
    const int wave = t >> 6;
    const int lane = t & 63;
    const int quad = lane >> 4;
    const int l15  = lane & 15;
    const int wr0  = (wave & 1) * 64;
    const int wc0  = (wave >> 1) * 128;
    const int row0 = blockIdx.x * 128;
    const int p8   = (quad ^ ((l15 >> 1) & 3)) * 8;

    float bd1[16], bd2[16];
    int   bi1[16];
    #pragma unroll
    for (int s = 0; s < 16; s++) { bd1[s] = FLT_MAX; bd2[s] = FLT_MAX; bi1[s] = 0; }

    for (int cc = 0; cc < 8; cc++) {
        f32x4 acc[4][8];
        #pragma unroll
        for (int i = 0; i < 4; i++)
            #pragma unroll
            for (int j = 0; j < 8; j++) acc[i][j] = (f32x4){0.f, 0.f, 0.f, 0.f};

        for (int kc = 0; kc < 8; kc++) {
            __syncthreads();
            #pragma unroll
            for (int it = 0; it < 2; it++) {
                int s = it * 256 + t;
                int r = s >> 2;
                int g = (s & 3) ^ ((r >> 1) & 3);
                ld16(zh + (size_t)(row0 + r) * 256 + kc * 32 + g * 8, &Ah[s * 8]);
            }
            #pragma unroll
            for (int it = 0; it < 4; it++) {
                int s = it * 256 + t;
                int n = s >> 2;
                int g = (s & 3) ^ ((n >> 1) & 3);
                ld16(wh + (size_t)(cc * 256 + n) * 256 + kc * 32 + g * 8, &Bh[s * 8]);
            }
            __syncthreads();

            f16x8 ah[4];
            #pragma unroll
            for (int i = 0; i < 4; i++)
                ah[i] = *(const f16x8*)&Ah[(wr0 + i * 16 + l15) * 32 + p8];
            #pragma unroll
            for (int j = 0; j < 8; j++) {
                f16x8 bh = *(const f16x8*)&Bh[(wc0 + j * 16 + l15) * 32 + p8];
                #pragma unroll
                for (int i = 0; i < 4; i++)
                    acc[i][j] = __builtin_amdgcn_mfma_f32_16x16x32_f16(ah[i], bh, acc[i][j], 0, 0, 0);
            }
        }

        #pragma unroll
        for (int j = 0; j < 8; j++) {
            int c = cc * 256 + wc0 + j * 16 + l15;
            float csq = cbsq[c];
            #pragma unroll
            for (int i = 0; i < 4; i++) {
                #pragma unroll
                for (int r = 0; r < 4; r++) {
                    float d = fmaf(-2.0f, acc[i][j][r], csq);
                    int s = i * 4 + r;
                    if (d < bd1[s]) { bd2[s] = bd1[s]; bd1[s] = d; bi1[s] = c; }
                    else            { bd2[s] = fminf(bd2[s], d); }
                }
            }
        }
    }

    #pragma unroll
    for (int m = 1; m <= 8; m <<= 1) {
        #pragma unroll
        for (int s = 0; s < 16; s++) {
            float od1 = __shfl_xor(bd1[s], m, 64);
            int   oi1 = __shfl_xor(bi1[s], m, 64);
            float od2 = __shfl_xor(bd2[s], m, 64);
            if (od1 < bd1[s] || (od1 == bd1[s] && oi1 < bi1[s])) {
                bd2[s] = fminf(bd1[s], od2);
                bd1[s] = od1; bi1[s] = oi1;
            } else {
                bd2[s] = fminf(bd2[s], od1);
            }
        }
    }
    __syncthreads();
    if (l15 == 0) {
        #pragma unroll
        for (int i = 0; i < 4; i++)
            #pragma unroll
            for (int r = 0; r < 4; r++) {
                int row = wr0 + i * 16 + quad * 4 + r;
                rD[wave >> 1][row] = bd1[i * 4 + r];
                rI[wave >> 1][row] = bi1[i * 4 + r];
                r2[wave >> 1][row] = bd2[i * 4 + r];
            }
    }
    __syncthreads();
    if (t < 128) {
        float d1 = rD[0][t]; int i1 = rI[0][t]; float d2 = r2[0][t];
        float e1 = rD[1][t]; int j1 = rI[1][t]; float e2 = r2[1][t];
        if (e1 < d1 || (e1 == d1 && j1 < i1)) {
            d2 = fminf(d1, e2); d1 = e1; i1 = j1;
        } else {
            d2 = fminf(d2, e1);
        }
        int row = row0 + t;
        idx_out[row] = (float)i1;
        if (d2 - d1 < MARGIN) {
            int p = atomicAdd(fcount, 1);
            flags[p] = row;
        }
    }
}

// -------- phase 2: MFMA 3-pass exact-enough rescan of flagged rows --------
// Block = 64 flagged rows x 2048 codes. A (z rows) split hi/lo IN REGISTERS
// (loaded once per group); B (wh/wl) double-buffered in LDS, 256-code chunks.
// B tile = 256 codes x 32 halves = 1024 granules -> 4 staging iterations (r4 bug: was 2).
__global__ __launch_bounds__(256, 1)
void refine_kernel(const float* __restrict__ z, const _Float16* __restrict__ wh,
                   const _Float16* __restrict__ wl, const float* __restrict__ cbsq,
                   const int* __restrict__ fcount, const int* __restrict__ flags,
                   float* __restrict__ idx_f) {
    __shared__ _Float16 Bh[2][256 * 32];   // 16 KB x2
    __shared__ _Float16 Bl[2][256 * 32];   // 16 KB x2  -> 64 KB total

    const int t    = threadIdx.x;
    const int wave = t >> 6;
    const int lane = t & 63;
    const int quad = lane >> 4;
    const int l15  = lane & 15;
    const int wc0  = wave * 64;
    const int p8   = (quad ^ ((l15 >> 1) & 3)) * 8;
    const int count = *fcount;
    const int nb = (count + 63) >> 6;

    for (int g = blockIdx.x; g < nb; g += gridDim.x) {
        __syncthreads();   // protect LDS (incl. merge area) from previous group

        // ---- load A rows (this lane's 4 rows), split hi/lo into registers ----
        int rowi[4];
        f16x8 ah[8][4], al[8][4];
        #pragma unroll
        for (int i = 0; i < 4; i++) {
            int slot = (g << 6) + i * 16 + l15;
            rowi[i] = flags[slot < count ? slot : (g << 6)];
            #pragma unroll
            for (int kc = 0; kc < 8; kc++) {
                const float4* zp = (const float4*)(z + (size_t)rowi[i] * 256 + kc * 32 + quad * 8);
                float4 a = zp[0], b = zp[1];
                float v[8] = {a.x, a.y, a.z, a.w, b.x, b.y, b.z, b.w};
                _Float16 h[8], l[8];
                #pragma unroll
                for (int k = 0; k < 8; k++) {
                    h[k] = (_Float16)v[k];
                    l[k] = (_Float16)(v[k] - (float)h[k]);
                }
                ah[kc][i] = *(const f16x8*)h;
                al[kc][i] = *(const f16x8*)l;
            }
        }

        float bd[16]; int bi[16];
        #pragma unroll
        for (int s = 0; s < 16; s++) { bd[s] = FLT_MAX; bi[s] = 0; }

        // ---- prestage (cc=0, kc=0) into buf 0: FULL 256-code tile ----
        #pragma unroll
        for (int it = 0; it < 4; it++) {
            int s = it * 256 + t;
            int n = s >> 2;
            int gg = (s & 3) ^ ((n >> 1) & 3);
            size_t off = (size_t)n * 256 + gg * 8;
            ld16(wh + off, &Bh[0][s * 8]);
            ld16(wl + off, &Bl[0][s * 8]);
        }

        for (int cc = 0; cc < 8; cc++) {
            f32x4 acc[4][4];
            #pragma unroll
            for (int i = 0; i < 4; i++)
                #pragma unroll
                for (int j = 0; j < 4; j++) acc[i][j] = (f32x4){0.f, 0.f, 0.f, 0.f};

            #pragma unroll
            for (int kc = 0; kc < 8; kc++) {
                const int buf = kc & 1;
                __syncthreads();   // drains staging into buf + prev compute on buf^1
                // stage next step into buf^1
                int ncc = cc, nkc = kc + 1;
                if (nkc == 8) { ncc = cc + 1; nkc = 0; }
                if (ncc < 8) {
                    #pragma unroll
                    for (int it = 0; it < 4; it++) {
                        int s = it * 256 + t;
                        int n = s >> 2;
                        int gg = (s & 3) ^ ((n >> 1) & 3);
                        size_t off = (size_t)(ncc * 256 + n) * 256 + nkc * 32 + gg * 8;
                        ld16(wh + off, &Bh[buf ^ 1][s * 8]);
                        ld16(wl + off, &Bl[buf ^ 1][s * 8]);
                    }
                }
                // compute on buf
                #pragma unroll
                for (int j = 0; j < 4; j++) {
                    int offb = (wc0 + j * 16 + l15) * 32 + p8;
                    f16x8 bh = *(const f16x8*)&Bh[buf][offb];
                    f16x8 bl = *(const f16x8*)&Bl[buf][offb];
                    #pragma unroll
                    for (int i = 0; i < 4; i++) {
                        acc[i][j] = __builtin_amdgcn_mfma_f32_16x16x32_f16(ah[kc][i], bh, acc[i][j], 0, 0, 0);
                        acc[i][j] = __builtin_amdgcn_mfma_f32_16x16x32_f16(ah[kc][i], bl, acc[i][j], 0, 0, 0);
                        acc[i][j] = __builtin_amdgcn_mfma_f32_16x16x32_f16(al[kc][i], bh, acc[i][j], 0, 0, 0);
                    }
                }
            }

            // epilogue: codes ascend in (cc, j) per lane -> first-min kept
            #pragma unroll
            for (int j = 0; j < 4; j++) {
                int c = cc * 256 + wc0 + j * 16 + l15;
                float csq = cbsq[c];
                #pragma unroll
                for (int i = 0; i < 4; i++) {
                    #pragma unroll
                    for (int r = 0; r < 4; r++) {
                        float d = fmaf(-2.0f, acc[i][j][r], csq);
                        int s = i * 4 + r;
                        if (d < bd[s]) { bd[s] = d; bi[s] = c; }
                    }
                }
            }
        }

        // lane reduction over l15 (codes), tie -> smaller index
        #pragma unroll
        for (int m = 1; m <= 8; m <<= 1) {
            #pragma unroll
            for (int s = 0; s < 16; s++) {
                float od = __shfl_xor(bd[s], m, 64);
                int   oi = __shfl_xor(bi[s], m, 64);
                if (od < bd[s] || (od == bd[s] && oi < bi[s])) { bd[s] = od; bi[s] = oi; }
            }
        }
        __syncthreads();   // all compute done; safe to reuse B LDS as merge area
        float* rD = (float*)&Bh[0][0];   // 4 waves x 64 rows
        int*   rI = (int*)&Bl[0][0];
        if (l15 == 0) {
            #pragma unroll
            for (int i = 0; i < 4; i++)
                #pragma unroll
                for (int r = 0; r < 4; r++) {
                    int row = i * 16 + quad * 4 + r;
                    rD[wave * 64 + row] = bd[i * 4 + r];
                    rI[wave * 64 + row] = bi[i * 4 + r];
                }
        }
        __syncthreads();
        if (t < 64) {
            float d1 = rD[t]; int i1 = rI[t];
            #pragma unroll
            for (int w = 1; w < 4; w++) {
                float dw = rD[w * 64 + t]; int iw = rI[w * 64 + t];
                if (dw < d1 || (dw == d1 && iw < i1)) { d1 = dw; i1 = iw; }
            }
            int slot = (g << 6) + t;
            if (slot < count) idx_f[flags[slot]] = (float)i1;
        }
    }
}

// -------- gather + STE + commitment partial + histogram: one wave per row --------
__global__ void gather_kernel(const float* __restrict__ z, const float* __restrict__ cb,
                              const float* __restrict__ idx_f, float* __restrict__ out,
                              int* __restrict__ usage, float* __restrict__ accum) {
    int lane = threadIdx.x & 63;
    int wid  = (blockIdx.x * blockDim.x + threadIdx.x) >> 6;
    const float4* z4  = (const float4*)z;
    const float4* cb4 = (const float4*)cb;
    float4* o4 = (float4*)out;

    float local = 0.0f;
    for (int r = wid; r < NROWS; r += 2048) {
        int idx = (int)idx_f[r];
        float4 w  = cb4[(size_t)idx * 64 + lane];
        float4 zv = z4[(size_t)r * 64 + lane];
        float4 d;
        d.x = w.x - zv.x; d.y = w.y - zv.y; d.z = w.z - zv.z; d.w = w.w - zv.w;
        float4 o;
        o.x = zv.x + d.x; o.y = zv.y + d.y; o.z = zv.z + d.z; o.w = zv.w + d.w;
        o4[(size_t)r * 64 + lane] = o;
        local = fmaf(d.x, d.x, local);
        local = fmaf(d.y, d.y, local);
        local = fmaf(d.z, d.z, local);
        local = fmaf(d.w, d.w, local);
        if (lane == 0) atomicAdd(&usage[idx], 1);
    }
    #pragma unroll
    for (int m = 32; m >= 1; m >>= 1) local += __shfl_xor(local, m, 64);
    if (lane == 0) atomicAdd(accum, local);
}

// -------- scalars: commitment mean + entropy loss --------
__global__ void finalize_kernel(const int* __restrict__ usage, const float* __restrict__ accum,
                                float* __restrict__ out2) {
    __shared__ float red[256];
    int t = threadIdx.x;
    float e = 0.0f;
    for (int b = t; b < NCODES; b += 256) {
        float p = (float)usage[b] * (1.0f / 65536.0f);
        e -= p * logf(p + 1e-10f);
    }
    red[t] = e;
    __syncthreads();
    if (t == 0) {
        float s = 0.0f;
        for (int k = 0; k < 256; k++) s += red[k];
        out2[0] = accum[0] / 16777216.0f;
        out2[1] = logf(2048.0f) - s;
    }
}

extern "C" void kernel_launch(void* const* d_in, const int* in_sizes, int n_in,
                              void* d_out, int out_size, void* d_ws, size_t ws_size,
                              hipStream_t stream) {
    const float* z  = (const float*)d_in[0];
    const float* cb = (const float*)d_in[1];

    float* out   = (float*)d_out;
    float* idx_f = out + (size_t)NROWS * DIM;
    float* out2  = idx_f + NROWS;

    _Float16* zh = (_Float16*)d_out;   // scratch in zq region, overwritten by gather

    _Float16* wh    = (_Float16*)((char*)d_ws + WS_WH);
    _Float16* wl    = (_Float16*)((char*)d_ws + WS_WL);
    float*    cbsq  = (float*)((char*)d_ws + WS_CBSQ);
    int*      usage = (int*)((char*)d_ws + WS_USAGE);
    float*    accum = (float*)((char*)d_ws + WS_ACCUM);
    int*      fcount= (int*)((char*)d_ws + WS_FCOUNT);
    int*      flags = (int*)((char*)d_ws + WS_FLAGS);

    hipMemsetAsync((char*)d_ws + WS_USAGE, 0, 8200, stream);   // usage + accum + fcount
    split_hi_kernel<<<8192, 256, 0, stream>>>(z, zh);
    cbprep_kernel<<<512, 256, 0, stream>>>(cb, wh, wl, cbsq);
    argmin_kernel<<<512, 256, 0, stream>>>(zh, wh, cbsq, idx_f, fcount, flags);
    refine_kernel<<<256, 256, 0, stream>>>(z, wh, wl, cbsq, fcount, flags, idx_f);
    gather_kernel<<<512, 256, 0, stream>>>(z, cb, idx_f, out, usage, accum);
    finalize_kernel<<<1, 256, 0, stream>>>(usage, accum, out2);
}